// Round 13
// baseline (353.648 us; speedup 1.0000x reference)
//
#include <hip/hip_runtime.h>
#include <math.h>

#define NPATH 8192
#define NT    2048
#define DEG   20                // Chebyshev degree; 21 coefficients
#define NCF   (DEG + 1)
#define CPAD  24                // padded coeff stride per path
#define LM    (-3.75f)          // lv-range center  (lv in [-7, -0.5])
#define LR    (3.25f)           // lv-range half-width
#define SFX   2.8853900817779268f   // 2*log2(e)
#define LFX   1.4426950408889634f   // log2(e)

typedef float v2f __attribute__((ext_vector_type(2)));
typedef float v4f __attribute__((ext_vector_type(4)));

// ws float layout
#define W2P_F   0        // v2f w2pairs[k*32+j] = {W2dr[j][k], W2df[j][k]}  (2048 floats)
#define W1VP_F  2048     // v2f w1v pairs [32]
#define W3P_F   2112     // v2f w3 pairs  [32]
#define B2P_F   2176     // v2f b2 pairs  [32]
#define CST_F   2240     // b3dr, b3df, dt
#define CTAB_B  16384    // byte offset: v2f ctab[path][CPAD] = Chebyshev coeffs {F=drift*dt, G=diffusion}

__device__ __forceinline__ v2f vsplat(float x) { return (v2f){x, x}; }
__device__ __forceinline__ v2f vfma(v2f a, v2f b, v2f c) { return __builtin_elementwise_fma(a, b, c); }

__device__ __forceinline__ float tanh1(float z) {   // tanh(z) via exp2
    float e = __builtin_amdgcn_exp2f(SFX * z);
    return fmaf(__builtin_amdgcn_rcpf(1.0f + e), -2.0f, 1.0f);
}
__device__ __forceinline__ float sig1(float z) {    // sigmoid(z)
    float e = __builtin_amdgcn_exp2f(-LFX * z);
    return __builtin_amdgcn_rcpf(1.0f + e);
}
__device__ __forceinline__ v2f tanh2(v2f z) {
    v2f r; r.x = tanh1(z.x); r.y = tanh1(z.y); return r;
}

__global__ void prep_kernel(const float* __restrict__ drw1,
                            const float* __restrict__ drw2, const float* __restrict__ drb2,
                            const float* __restrict__ drw3, const float* __restrict__ drb3,
                            const float* __restrict__ dfw1,
                            const float* __restrict__ dfw2, const float* __restrict__ dfb2,
                            const float* __restrict__ dfw3, const float* __restrict__ dfb3,
                            const float* __restrict__ dtp, float* __restrict__ ws)
{
    int tid = threadIdx.x;
    for (int idx = tid; idx < 1024; idx += 256) {
        int k = idx >> 5, j = idx & 31;
        ws[W2P_F + 2 * idx]     = drw2[j * 32 + k];   // W2[j][k] pairs, k-major
        ws[W2P_F + 2 * idx + 1] = dfw2[j * 32 + k];
    }
    if (tid < 32) {
        ws[W1VP_F + 2 * tid]     = drw1[tid * 16 + 15];
        ws[W1VP_F + 2 * tid + 1] = dfw1[tid * 16 + 15];
        ws[W3P_F + 2 * tid]      = drw3[tid];
        ws[W3P_F + 2 * tid + 1]  = dfw3[tid];
        ws[B2P_F + 2 * tid]      = drb2[tid];
        ws[B2P_F + 2 * tid + 1]  = dfb2[tid];
    }
    if (tid == 0) {
        ws[CST_F]     = drb3[0];
        ws[CST_F + 1] = dfb3[0];
        ws[CST_F + 2] = dtp[0];
    }
}

// One 64-lane wave per path. Lane j evaluates both nets at Chebyshev node
// lv_j = LM + LR*cos(theta_j), then the wave computes the 21 Chebyshev
// coefficients of {drift*dt, diffusion} by cosine-weighted butterfly sums.
// Weights via wave-uniform global reads -> pipelined s_loads; two chunks of
// 16 accumulators (no spills, verified r10-12).
__global__ __launch_bounds__(64) void build_kernel(
    const float* __restrict__ sig,
    const float* __restrict__ drw1, const float* __restrict__ drb1,
    const float* __restrict__ dfw1, const float* __restrict__ dfb1,
    const float* __restrict__ wconst, v2f* __restrict__ ctab)
{
    const int p = blockIdx.x;
    const int j = threadIdx.x;
    __shared__ v2f spv[32];            // pre pairs {dr, df} per hidden unit
    if (j < 64) {
        int u = j & 31, net = j >> 5;
        const float* w1 = net ? dfw1 : drw1;
        const float* b1 = net ? dfb1 : drb1;
        float acc = b1[u];
#pragma unroll
        for (int m = 0; m < 15; ++m) acc = fmaf(sig[p * 15 + m], w1[u * 16 + m], acc);
        ((float*)spv)[2 * u + net] = acc;
    }
    __syncthreads();

    const float th = ((float)j + 0.5f) * (float)(M_PI / 64.0);
    const float xj = __cosf(th);
    const float v  = (LM + LR * xj) + 4.0f;        // v = lv + 4 at this node

    const v2f* __restrict__ w2p  = (const v2f*)(wconst + W2P_F);
    const v2f* __restrict__ w1vp = (const v2f*)(wconst + W1VP_F);
    const v2f* __restrict__ w3p  = (const v2f*)(wconst + W3P_F);
    const v2f* __restrict__ b2p  = (const v2f*)(wconst + B2P_F);

    v2f z3 = (v2f){wconst[CST_F], wconst[CST_F + 1]};

#pragma unroll
    for (int c = 0; c < 2; ++c) {          // two chunks of 16 output units
        v2f acc[16];
#pragma unroll
        for (int q = 0; q < 16; ++q) acc[q] = b2p[c * 16 + q];

#pragma unroll 8
        for (int k = 0; k < 32; ++k) {     // h recomputed per chunk
            v2f pre = spv[k];
            v2f z   = vfma(vsplat(v), w1vp[k], pre);
            v2f h   = tanh2(z);
            const v2f* col = w2p + k * 32 + c * 16;   // uniform -> s_load
#pragma unroll
            for (int q = 0; q < 16; ++q) acc[q] = vfma(col[q], h, acc[q]);
        }
#pragma unroll
        for (int q = 0; q < 16; ++q) {
            v2f a2 = tanh2(acc[q]);
            z3 = vfma(w3p[c * 16 + q], a2, z3);
        }
    }

    float dt = wconst[CST_F + 2];
    v2f Fj;
    Fj.x = 3.0f * tanh1(z3.x) * dt;                // F = drift * dt
    Fj.y = sig1(z3.y) + 0.1f;                      // G = diffusion
    // c_k = (2-delta_k0)/64 * sum_j Fj * cos(k*theta_j)
    for (int k = 0; k < NCF; ++k) {
        float ck = __cosf((float)k * th);
        v2f t; t.x = Fj.x * ck; t.y = Fj.y * ck;
#pragma unroll
        for (int m = 1; m < 64; m <<= 1) {
            t.x += __shfl_xor(t.x, m);
            t.y += __shfl_xor(t.y, m);
        }
        float s = (k == 0) ? (1.0f / 64.0f) : (2.0f / 64.0f);
        if (j == k) ctab[(size_t)p * CPAD + k] = (v2f){t.x * s, t.y * s};
    }
}

// One lane per path, no LDS. Coefficients live in 42 VGPRs; per step the
// {F,G} pair is evaluated by packed-f32 Clenshaw (chain = 20 pk_fma), so the
// serial recurrence never touches memory. dW through the 4-group register
// pipeline; exp2+store off-chain.
__global__ __launch_bounds__(64) void scan_kernel(
    const float* __restrict__ init_var,
    const float* __restrict__ dW,
    const float* __restrict__ ws,
    float* __restrict__ out)
{
    const int lane = threadIdx.x;
    const int path = blockIdx.x * 64 + lane;
    const v2f* __restrict__ ct = (const v2f*)((const char*)ws + CTAB_B) + (size_t)path * CPAD;

    v2f c[NCF];
#pragma unroll
    for (int k = 0; k < NCF; ++k) c[k] = ct[k];

    float lv = logf(fminf(fmaxf(init_var[path], 0.005f), 0.2f));
    const float NX1 = 1.0f / LR;                   // x = (lv - LM)/LR
    const float NX0 = -LM / LR;
    const float* __restrict__ dwrow = dW + (size_t)path * NT;
    float* __restrict__ outp = out + path;

    auto STEP = [&](float dw, int tt) {
        float x  = fmaf(lv, NX1, NX0);
        float x2 = x + x;
        v2f bk1 = vsplat(0.0f), bk2 = vsplat(0.0f);
#pragma unroll
        for (int k = DEG; k >= 1; --k) {
            v2f bk = vfma(vsplat(x2), bk1, c[k] - bk2);
            bk2 = bk1; bk1 = bk;
        }
        v2f val = vfma(vsplat(x), bk1, c[0] - bk2);   // {F, G}
        lv = fmaf(val.y, dw, lv + val.x);
        lv = __builtin_amdgcn_fmed3f(lv, -7.0f, -0.5f);
        float ev = __builtin_amdgcn_exp2f(lv * LFX);  // off-chain
        __builtin_nontemporal_store(ev, outp + (size_t)tt * NPATH);
    };

    // 16-step-deep dW register pipeline (plain cached loads; lines reused 4x)
    v4f buf0 = *(const v4f*)(dwrow + 0);
    v4f buf1 = *(const v4f*)(dwrow + 4);
    v4f buf2 = *(const v4f*)(dwrow + 8);
    v4f buf3 = *(const v4f*)(dwrow + 12);
    for (int t = 0; t < NT; t += 4) {
        v4f cur = buf0;
        buf0 = buf1; buf1 = buf2; buf2 = buf3;
        if (t + 16 < NT) buf3 = *(const v4f*)(dwrow + t + 16);
        STEP(cur.x, t);
        STEP(cur.y, t + 1);
        STEP(cur.z, t + 2);
        STEP(cur.w, t + 3);
    }
}

extern "C" void kernel_launch(void* const* d_in, const int* in_sizes, int n_in,
                              void* d_out, int out_size, void* d_ws, size_t ws_size,
                              hipStream_t stream) {
    const float* init_var = (const float*)d_in[0];
    const float* sig      = (const float*)d_in[1];
    const float* dW       = (const float*)d_in[2];
    const float* dtp      = (const float*)d_in[3];
    const float* drw1     = (const float*)d_in[4];
    const float* drb1     = (const float*)d_in[5];
    const float* drw2     = (const float*)d_in[6];
    const float* drb2     = (const float*)d_in[7];
    const float* drw3     = (const float*)d_in[8];
    const float* drb3     = (const float*)d_in[9];
    const float* dfw1     = (const float*)d_in[10];
    const float* dfb1     = (const float*)d_in[11];
    const float* dfw2     = (const float*)d_in[12];
    const float* dfb2     = (const float*)d_in[13];
    const float* dfw3     = (const float*)d_in[14];
    const float* dfb3     = (const float*)d_in[15];
    float* out = (float*)d_out;
    float* ws  = (float*)d_ws;

    hipLaunchKernelGGL(prep_kernel, dim3(1), dim3(256), 0, stream,
                       drw1, drw2, drb2, drw3, drb3,
                       dfw1, dfw2, dfb2, dfw3, dfb3, dtp, ws);
    hipLaunchKernelGGL(build_kernel, dim3(NPATH), dim3(64), 0, stream,
                       sig, drw1, drb1, dfw1, dfb1,
                       ws, (v2f*)((char*)ws + CTAB_B));
    hipLaunchKernelGGL(scan_kernel, dim3(NPATH / 64), dim3(64), 0, stream,
                       init_var, dW, ws, out);
}

// Round 14
// 249.709 us; speedup vs baseline: 1.4162x; 1.4162x over previous
//
#include <hip/hip_runtime.h>
#include <math.h>

#define NPATH 8192
#define NT    2048
#define NCF   11                // even/odd monomial coeffs each (deg 10 in y)
#define CPAD  24                // padded v2f stride per path
#define LM    (-3.75f)          // lv-range center  (lv in [-7, -0.5])
#define LR    (3.25f)           // lv-range half-width
#define SFX   2.8853900817779268f   // 2*log2(e)
#define LFX   1.4426950408889634f   // log2(e)

typedef float v2f __attribute__((ext_vector_type(2)));
typedef float v4f __attribute__((ext_vector_type(4)));

// ws float layout
#define W2P_F   0        // v2f w2pairs[k*32+j] = {W2dr[j][k], W2df[j][k]}  (2048 floats)
#define W1VP_F  2048     // v2f w1v pairs [32]
#define W3P_F   2112     // v2f w3 pairs  [32]
#define B2P_F   2176     // v2f b2 pairs  [32]
#define CST_F   2240     // b3dr, b3df, dt
#define CTAB_B  16384    // byte offset: v2f ctab[path][CPAD] = {mE0..mE10, mO0..mO10}

// TM[i][k] = coefficient of y^k in T_i(y), i,k in [0,10] (row-major, 11x11)
__device__ const float TMAT[121] = {
  1,0,0,0,0,0,0,0,0,0,0,
  0,1,0,0,0,0,0,0,0,0,0,
  -1,0,2,0,0,0,0,0,0,0,0,
  0,-3,0,4,0,0,0,0,0,0,0,
  1,0,-8,0,8,0,0,0,0,0,0,
  0,5,0,-20,0,16,0,0,0,0,0,
  -1,0,18,0,-48,0,32,0,0,0,0,
  0,-7,0,56,0,-112,0,64,0,0,0,
  1,0,-32,0,160,0,-256,0,128,0,0,
  0,9,0,-120,0,432,0,-576,0,256,0,
  -1,0,50,0,-400,0,1120,0,-1280,0,512
};

__device__ __forceinline__ v2f vsplat(float x) { return (v2f){x, x}; }
__device__ __forceinline__ v2f vfma(v2f a, v2f b, v2f c) { return __builtin_elementwise_fma(a, b, c); }

__device__ __forceinline__ float tanh1(float z) {   // tanh(z) via exp2
    float e = __builtin_amdgcn_exp2f(SFX * z);
    return fmaf(__builtin_amdgcn_rcpf(1.0f + e), -2.0f, 1.0f);
}
__device__ __forceinline__ float sig1(float z) {    // sigmoid(z)
    float e = __builtin_amdgcn_exp2f(-LFX * z);
    return __builtin_amdgcn_rcpf(1.0f + e);
}
__device__ __forceinline__ v2f tanh2(v2f z) {
    v2f r; r.x = tanh1(z.x); r.y = tanh1(z.y); return r;
}

__global__ void prep_kernel(const float* __restrict__ drw1,
                            const float* __restrict__ drw2, const float* __restrict__ drb2,
                            const float* __restrict__ drw3, const float* __restrict__ drb3,
                            const float* __restrict__ dfw1,
                            const float* __restrict__ dfw2, const float* __restrict__ dfb2,
                            const float* __restrict__ dfw3, const float* __restrict__ dfb3,
                            const float* __restrict__ dtp, float* __restrict__ ws)
{
    int tid = threadIdx.x;
    for (int idx = tid; idx < 1024; idx += 256) {
        int k = idx >> 5, j = idx & 31;
        ws[W2P_F + 2 * idx]     = drw2[j * 32 + k];   // W2[j][k] pairs, k-major
        ws[W2P_F + 2 * idx + 1] = dfw2[j * 32 + k];
    }
    if (tid < 32) {
        ws[W1VP_F + 2 * tid]     = drw1[tid * 16 + 15];
        ws[W1VP_F + 2 * tid + 1] = dfw1[tid * 16 + 15];
        ws[W3P_F + 2 * tid]      = drw3[tid];
        ws[W3P_F + 2 * tid + 1]  = dfw3[tid];
        ws[B2P_F + 2 * tid]      = drb2[tid];
        ws[B2P_F + 2 * tid + 1]  = dfb2[tid];
    }
    if (tid == 0) {
        ws[CST_F]     = drb3[0];
        ws[CST_F + 1] = dfb3[0];
        ws[CST_F + 2] = dtp[0];
    }
}

// One 64-lane wave per path. Lane j evaluates both nets at Cheb node
// x_j = cos((j+.5)pi/64), lv_j = LM + LR*x_j. Even/odd split via partner
// exchange (shfl_xor 63), 32-lane DCT butterflies give Cheb coeffs of
// E(y),O(y) (y = 2x^2-1, deg 10 each), then per-lane Cheb->monomial
// conversion through the constant T-matrix. Weights via wave-uniform
// global reads -> s_loads; 2x16-acc MLP structure (no spills, r10-13).
__global__ __launch_bounds__(64) void build_kernel(
    const float* __restrict__ sig,
    const float* __restrict__ drw1, const float* __restrict__ drb1,
    const float* __restrict__ dfw1, const float* __restrict__ dfb1,
    const float* __restrict__ wconst, v2f* __restrict__ ctab)
{
    const int p = blockIdx.x;
    const int j = threadIdx.x;
    __shared__ v2f spv[32];            // pre pairs {dr, df} per hidden unit
    {
        int u = j & 31, net = j >> 5;
        const float* w1 = net ? dfw1 : drw1;
        const float* b1 = net ? dfb1 : drb1;
        float acc = b1[u];
#pragma unroll
        for (int m = 0; m < 15; ++m) acc = fmaf(sig[p * 15 + m], w1[u * 16 + m], acc);
        ((float*)spv)[2 * u + net] = acc;
    }
    __syncthreads();

    const float th = ((float)j + 0.5f) * (float)(M_PI / 64.0);
    const float xj = __cosf(th);
    const float v  = (LM + LR * xj) + 4.0f;        // v = lv + 4 at this node

    const v2f* __restrict__ w2p  = (const v2f*)(wconst + W2P_F);
    const v2f* __restrict__ w1vp = (const v2f*)(wconst + W1VP_F);
    const v2f* __restrict__ w3p  = (const v2f*)(wconst + W3P_F);
    const v2f* __restrict__ b2p  = (const v2f*)(wconst + B2P_F);

    v2f z3 = (v2f){wconst[CST_F], wconst[CST_F + 1]};

#pragma unroll
    for (int c = 0; c < 2; ++c) {          // two chunks of 16 output units
        v2f acc[16];
#pragma unroll
        for (int q = 0; q < 16; ++q) acc[q] = b2p[c * 16 + q];

#pragma unroll 8
        for (int k = 0; k < 32; ++k) {     // h recomputed per chunk
            v2f pre = spv[k];
            v2f z   = vfma(vsplat(v), w1vp[k], pre);
            v2f h   = tanh2(z);
            const v2f* col = w2p + k * 32 + c * 16;   // uniform -> s_load
#pragma unroll
            for (int q = 0; q < 16; ++q) acc[q] = vfma(col[q], h, acc[q]);
        }
#pragma unroll
        for (int q = 0; q < 16; ++q) {
            v2f a2 = tanh2(acc[q]);
            z3 = vfma(w3p[c * 16 + q], a2, z3);
        }
    }

    float dt = wconst[CST_F + 2];
    v2f Fj;
    Fj.x = 3.0f * tanh1(z3.x) * dt;                // F = drift * dt
    Fj.y = sig1(z3.y) + 0.1f;                      // G = diffusion

    // even/odd split: E = (F(x)+F(-x))/2, O = (F(x)-F(-x))/(2x); partner
    // lane is j^63 (x -> -x). Valid in both halves (x<0 flips both signs).
    v2f Fp;
    Fp.x = __shfl_xor(Fj.x, 63);
    Fp.y = __shfl_xor(Fj.y, 63);
    v2f E = (Fj + Fp) * 0.5f;
    float rx = 0.5f * __builtin_amdgcn_rcpf(xj);
    v2f O = (Fj - Fp) * vsplat(rx);

    // y-nodes: jj = j (half0) / 63-j (half1); theta2 = (jj+.5)pi/32.
    int jj = (j < 32) ? j : 63 - j;
    float th2 = ((float)jj + 0.5f) * (float)(M_PI / 32.0);

    v2f de[NCF], dq[NCF];
#pragma unroll
    for (int k = 0; k < NCF; ++k) {
        float ck = __cosf((float)k * th2);
        v2f tE = E * vsplat(ck);
        v2f tO = O * vsplat(ck);
#pragma unroll
        for (int m = 1; m < 32; m <<= 1) {         // 32-lane butterflies (halves independent)
            tE.x += __shfl_xor(tE.x, m); tE.y += __shfl_xor(tE.y, m);
            tO.x += __shfl_xor(tO.x, m); tO.y += __shfl_xor(tO.y, m);
        }
        float s = (k == 0) ? (1.0f / 32.0f) : (2.0f / 32.0f);
        de[k] = tE * vsplat(s);
        dq[k] = tO * vsplat(s);
    }

    // Cheb -> monomial: lane kk computes m_kk = sum_i d_i * TM[i][kk].
    // Lanes 0..10 -> E coeffs, lanes 16..26 -> O coeffs.
    int kk = j & 15; if (kk > 10) kk = 10;
    v2f m = vsplat(0.0f);
#pragma unroll
    for (int i = 0; i < NCF; ++i) {
        float a = TMAT[i * 11 + kk];               // dynamic kk -> rodata load (off-chain)
        m = vfma((j < 16) ? de[i] : dq[i], vsplat(a), m);
    }
    if (j < 11)                 ctab[(size_t)p * CPAD + j]            = m;
    else if (j >= 16 && j < 27) ctab[(size_t)p * CPAD + 11 + (j - 16)] = m;
}

// One lane per path, no LDS. 22 NAMED v2f coefficients, asm-pinned into
// registers (defeats invariant-load remat, the r13 killer); waves_per_eu(1,2)
// removes the phantom occupancy register cap (real occupancy is 1 wave/CU).
// Per step: y = 2x^2-1, two parallel 10-deep pk-Horner chains, combine,
// update. No memory on the chain at all.
__global__ __launch_bounds__(64) __attribute__((amdgpu_waves_per_eu(1, 2)))
void scan_kernel(
    const float* __restrict__ init_var,
    const float* __restrict__ dW,
    const float* __restrict__ ws,
    float* __restrict__ out)
{
    const int lane = threadIdx.x;
    const int path = blockIdx.x * 64 + lane;
    const v2f* __restrict__ ct = (const v2f*)((const char*)ws + CTAB_B) + (size_t)path * CPAD;

    v2f e0 = ct[0], e1 = ct[1], e2 = ct[2], e3 = ct[3], e4 = ct[4], e5 = ct[5];
    v2f e6 = ct[6], e7 = ct[7], e8 = ct[8], e9 = ct[9], e10 = ct[10];
    v2f q0 = ct[11], q1 = ct[12], q2 = ct[13], q3 = ct[14], q4 = ct[15], q5 = ct[16];
    v2f q6 = ct[17], q7 = ct[18], q8 = ct[19], q9 = ct[20], q10 = ct[21];
    asm volatile("" : "+v"(e0), "+v"(e1), "+v"(e2), "+v"(e3), "+v"(e4), "+v"(e5),
                      "+v"(e6), "+v"(e7), "+v"(e8), "+v"(e9), "+v"(e10));
    asm volatile("" : "+v"(q0), "+v"(q1), "+v"(q2), "+v"(q3), "+v"(q4), "+v"(q5),
                      "+v"(q6), "+v"(q7), "+v"(q8), "+v"(q9), "+v"(q10));

    float lv = logf(fminf(fmaxf(init_var[path], 0.005f), 0.2f));
    const float NX1 = 1.0f / LR;                   // x = (lv - LM)/LR
    const float NX0 = -LM / LR;
    const float* __restrict__ dwrow = dW + (size_t)path * NT;
    float* __restrict__ outp = out + path;

    auto STEP = [&](float dw, int tt) {
        float x = fmaf(lv, NX1, NX0);
        float y = fmaf(x + x, x, -1.0f);
        v2f yv = vsplat(y);
        v2f bE = vfma(yv, e10, e9);
        v2f bO = vfma(yv, q10, q9);
        bE = vfma(yv, bE, e8);  bO = vfma(yv, bO, q8);
        bE = vfma(yv, bE, e7);  bO = vfma(yv, bO, q7);
        bE = vfma(yv, bE, e6);  bO = vfma(yv, bO, q6);
        bE = vfma(yv, bE, e5);  bO = vfma(yv, bO, q5);
        bE = vfma(yv, bE, e4);  bO = vfma(yv, bO, q4);
        bE = vfma(yv, bE, e3);  bO = vfma(yv, bO, q3);
        bE = vfma(yv, bE, e2);  bO = vfma(yv, bO, q2);
        bE = vfma(yv, bE, e1);  bO = vfma(yv, bO, q1);
        bE = vfma(yv, bE, e0);  bO = vfma(yv, bO, q0);
        v2f val = vfma(vsplat(x), bO, bE);         // {F = drift*dt, G = diffusion}
        lv = fmaf(val.y, dw, lv + val.x);
        lv = __builtin_amdgcn_fmed3f(lv, -7.0f, -0.5f);
        float ev = __builtin_amdgcn_exp2f(lv * LFX);   // off-chain
        __builtin_nontemporal_store(ev, outp + (size_t)tt * NPATH);
    };

    // 16-step-deep dW register pipeline (plain cached loads; lines reused 4x)
    v4f buf0 = *(const v4f*)(dwrow + 0);
    v4f buf1 = *(const v4f*)(dwrow + 4);
    v4f buf2 = *(const v4f*)(dwrow + 8);
    v4f buf3 = *(const v4f*)(dwrow + 12);
    for (int t = 0; t < NT; t += 4) {
        v4f cur = buf0;
        buf0 = buf1; buf1 = buf2; buf2 = buf3;
        if (t + 16 < NT) buf3 = *(const v4f*)(dwrow + t + 16);
        STEP(cur.x, t);
        STEP(cur.y, t + 1);
        STEP(cur.z, t + 2);
        STEP(cur.w, t + 3);
    }
}

extern "C" void kernel_launch(void* const* d_in, const int* in_sizes, int n_in,
                              void* d_out, int out_size, void* d_ws, size_t ws_size,
                              hipStream_t stream) {
    const float* init_var = (const float*)d_in[0];
    const float* sig      = (const float*)d_in[1];
    const float* dW       = (const float*)d_in[2];
    const float* dtp      = (const float*)d_in[3];
    const float* drw1     = (const float*)d_in[4];
    const float* drb1     = (const float*)d_in[5];
    const float* drw2     = (const float*)d_in[6];
    const float* drb2     = (const float*)d_in[7];
    const float* drw3     = (const float*)d_in[8];
    const float* drb3     = (const float*)d_in[9];
    const float* dfw1     = (const float*)d_in[10];
    const float* dfb1     = (const float*)d_in[11];
    const float* dfw2     = (const float*)d_in[12];
    const float* dfb2     = (const float*)d_in[13];
    const float* dfw3     = (const float*)d_in[14];
    const float* dfb3     = (const float*)d_in[15];
    float* out = (float*)d_out;
    float* ws  = (float*)d_ws;

    hipLaunchKernelGGL(prep_kernel, dim3(1), dim3(256), 0, stream,
                       drw1, drw2, drb2, drw3, drb3,
                       dfw1, dfw2, dfb2, dfw3, dfb3, dtp, ws);
    hipLaunchKernelGGL(build_kernel, dim3(NPATH), dim3(64), 0, stream,
                       sig, drw1, drb1, dfw1, dfb1,
                       ws, (v2f*)((char*)ws + CTAB_B));
    hipLaunchKernelGGL(scan_kernel, dim3(NPATH / 64), dim3(64), 0, stream,
                       init_var, dW, ws, out);
}

// Round 15
// 225.580 us; speedup vs baseline: 1.5677x; 1.1070x over previous
//
#include <hip/hip_runtime.h>
#include <math.h>

#define NPATH 8192
#define NT    2048
#define NCF   8                 // even/odd coeffs each (deg 7 in y)
#define CPAD  16                // padded v2f stride per path
#define LM    (-3.75f)          // lv-range center  (lv in [-7, -0.5])
#define LR    (3.25f)           // lv-range half-width
#define SFX   2.8853900817779268f   // 2*log2(e)
#define LFX   1.4426950408889634f   // log2(e)

typedef float v2f __attribute__((ext_vector_type(2)));
typedef float v4f __attribute__((ext_vector_type(4)));

// ws float layout
#define W2P_F   0        // v2f w2pairs[k*32+j] = {W2dr[j][k], W2df[j][k]}  (2048 floats)
#define W1VP_F  2048     // v2f w1v pairs [32]
#define W3P_F   2112     // v2f w3 pairs  [32]
#define B2P_F   2176     // v2f b2 pairs  [32]
#define CST_F   2240     // b3dr, b3df, dt
#define CTAB_B  16384    // byte offset: v2f ctab[path][CPAD] = {mE0..mE7, mO0..mO7}

// TM[i][k] = coefficient of y^k in T_i(y), i,k in [0,7] (row-major, 8x8)
__device__ const float TMAT[64] = {
  1,0,0,0,0,0,0,0,
  0,1,0,0,0,0,0,0,
  -1,0,2,0,0,0,0,0,
  0,-3,0,4,0,0,0,0,
  1,0,-8,0,8,0,0,0,
  0,5,0,-20,0,16,0,0,
  -1,0,18,0,-48,0,32,0,
  0,-7,0,56,0,-112,0,64
};

__device__ __forceinline__ v2f vsplat(float x) { return (v2f){x, x}; }
__device__ __forceinline__ v2f vfma(v2f a, v2f b, v2f c) { return __builtin_elementwise_fma(a, b, c); }

__device__ __forceinline__ float tanh1(float z) {   // tanh(z) via exp2
    float e = __builtin_amdgcn_exp2f(SFX * z);
    return fmaf(__builtin_amdgcn_rcpf(1.0f + e), -2.0f, 1.0f);
}
__device__ __forceinline__ float sig1(float z) {    // sigmoid(z)
    float e = __builtin_amdgcn_exp2f(-LFX * z);
    return __builtin_amdgcn_rcpf(1.0f + e);
}
__device__ __forceinline__ v2f tanh2(v2f z) {
    v2f r; r.x = tanh1(z.x); r.y = tanh1(z.y); return r;
}

__global__ void prep_kernel(const float* __restrict__ drw1,
                            const float* __restrict__ drw2, const float* __restrict__ drb2,
                            const float* __restrict__ drw3, const float* __restrict__ drb3,
                            const float* __restrict__ dfw1,
                            const float* __restrict__ dfw2, const float* __restrict__ dfb2,
                            const float* __restrict__ dfw3, const float* __restrict__ dfb3,
                            const float* __restrict__ dtp, float* __restrict__ ws)
{
    int tid = threadIdx.x;
    for (int idx = tid; idx < 1024; idx += 256) {
        int k = idx >> 5, j = idx & 31;
        ws[W2P_F + 2 * idx]     = drw2[j * 32 + k];   // W2[j][k] pairs, k-major
        ws[W2P_F + 2 * idx + 1] = dfw2[j * 32 + k];
    }
    if (tid < 32) {
        ws[W1VP_F + 2 * tid]     = drw1[tid * 16 + 15];
        ws[W1VP_F + 2 * tid + 1] = dfw1[tid * 16 + 15];
        ws[W3P_F + 2 * tid]      = drw3[tid];
        ws[W3P_F + 2 * tid + 1]  = dfw3[tid];
        ws[B2P_F + 2 * tid]      = drb2[tid];
        ws[B2P_F + 2 * tid + 1]  = dfb2[tid];
    }
    if (tid == 0) {
        ws[CST_F]     = drb3[0];
        ws[CST_F + 1] = dfb3[0];
        ws[CST_F + 2] = dtp[0];
    }
}

// One 64-lane wave per path. Lane j evaluates both nets at Cheb node
// x_j = cos((j+.5)pi/64); even/odd split via shfl_xor(63); 32-lane DCT
// butterflies give Cheb coeffs of E(y),O(y) (deg 7 each); per-lane
// Cheb->monomial conversion. Coefficients prescaled by 1/LR so the scan
// state is x (normalized lv) and the clamp is med3(x,-1,+1).
__global__ __launch_bounds__(64) void build_kernel(
    const float* __restrict__ sig,
    const float* __restrict__ drw1, const float* __restrict__ drb1,
    const float* __restrict__ dfw1, const float* __restrict__ dfb1,
    const float* __restrict__ wconst, v2f* __restrict__ ctab)
{
    const int p = blockIdx.x;
    const int j = threadIdx.x;
    __shared__ v2f spv[32];            // pre pairs {dr, df} per hidden unit
    {
        int u = j & 31, net = j >> 5;
        const float* w1 = net ? dfw1 : drw1;
        const float* b1 = net ? dfb1 : drb1;
        float acc = b1[u];
#pragma unroll
        for (int m = 0; m < 15; ++m) acc = fmaf(sig[p * 15 + m], w1[u * 16 + m], acc);
        ((float*)spv)[2 * u + net] = acc;
    }
    __syncthreads();

    const float th = ((float)j + 0.5f) * (float)(M_PI / 64.0);
    const float xj = __cosf(th);
    const float v  = (LM + LR * xj) + 4.0f;        // v = lv + 4 at this node

    const v2f* __restrict__ w2p  = (const v2f*)(wconst + W2P_F);
    const v2f* __restrict__ w1vp = (const v2f*)(wconst + W1VP_F);
    const v2f* __restrict__ w3p  = (const v2f*)(wconst + W3P_F);
    const v2f* __restrict__ b2p  = (const v2f*)(wconst + B2P_F);

    v2f z3 = (v2f){wconst[CST_F], wconst[CST_F + 1]};

#pragma unroll
    for (int c = 0; c < 2; ++c) {          // two chunks of 16 output units
        v2f acc[16];
#pragma unroll
        for (int q = 0; q < 16; ++q) acc[q] = b2p[c * 16 + q];

#pragma unroll 8
        for (int k = 0; k < 32; ++k) {     // h recomputed per chunk
            v2f pre = spv[k];
            v2f z   = vfma(vsplat(v), w1vp[k], pre);
            v2f h   = tanh2(z);
            const v2f* col = w2p + k * 32 + c * 16;   // uniform -> s_load
#pragma unroll
            for (int q = 0; q < 16; ++q) acc[q] = vfma(col[q], h, acc[q]);
        }
#pragma unroll
        for (int q = 0; q < 16; ++q) {
            v2f a2 = tanh2(acc[q]);
            z3 = vfma(w3p[c * 16 + q], a2, z3);
        }
    }

    float dt = wconst[CST_F + 2];
    v2f Fj;
    Fj.x = 3.0f * tanh1(z3.x) * dt * (1.0f / LR);  // F = drift*dt/LR  (x-space)
    Fj.y = (sig1(z3.y) + 0.1f) * (1.0f / LR);      // G = diffusion/LR (x-space)

    // even/odd split: E = (F(x)+F(-x))/2, O = (F(x)-F(-x))/(2x); partner
    // lane is j^63 (x -> -x).
    v2f Fp;
    Fp.x = __shfl_xor(Fj.x, 63);
    Fp.y = __shfl_xor(Fj.y, 63);
    v2f E = (Fj + Fp) * 0.5f;
    float rx = 0.5f * __builtin_amdgcn_rcpf(xj);
    v2f O = (Fj - Fp) * vsplat(rx);

    // y-nodes: jj = j (half0) / 63-j (half1); theta2 = (jj+.5)pi/32.
    int jj = (j < 32) ? j : 63 - j;
    float th2 = ((float)jj + 0.5f) * (float)(M_PI / 32.0);

    v2f de[NCF], dq[NCF];
#pragma unroll
    for (int k = 0; k < NCF; ++k) {
        float ck = __cosf((float)k * th2);
        v2f tE = E * vsplat(ck);
        v2f tO = O * vsplat(ck);
#pragma unroll
        for (int m = 1; m < 32; m <<= 1) {         // 32-lane butterflies (halves independent)
            tE.x += __shfl_xor(tE.x, m); tE.y += __shfl_xor(tE.y, m);
            tO.x += __shfl_xor(tO.x, m); tO.y += __shfl_xor(tO.y, m);
        }
        float s = (k == 0) ? (1.0f / 32.0f) : (2.0f / 32.0f);
        de[k] = tE * vsplat(s);
        dq[k] = tO * vsplat(s);
    }

    // Cheb -> monomial: lane kk computes m_kk = sum_i d_i * TM[i][kk].
    // Lanes 0..7 -> E coeffs, lanes 16..23 -> O coeffs.
    int kk = j & 15; if (kk > 7) kk = 7;
    v2f m = vsplat(0.0f);
#pragma unroll
    for (int i = 0; i < NCF; ++i) {
        float a = TMAT[i * 8 + kk];
        m = vfma((j < 16) ? de[i] : dq[i], vsplat(a), m);
    }
    if (j < 8)                  ctab[(size_t)p * CPAD + j]            = m;
    else if (j >= 16 && j < 24) ctab[(size_t)p * CPAD + 8 + (j - 16)] = m;
}

// One lane per path, no LDS, no memory on the chain. 16 NAMED v2f coeffs,
// asm-pinned (r13 remat killer). State is x = (lv-LM)/LR; per step:
// y = 2x^2-1, two 7-deep pk-Horner chains, combine, fma-update,
// med3(x,-1,1) clamp (inline consts), exp2 output off-chain.
__global__ __launch_bounds__(64) __attribute__((amdgpu_waves_per_eu(1, 2)))
void scan_kernel(
    const float* __restrict__ init_var,
    const float* __restrict__ dW,
    const float* __restrict__ ws,
    float* __restrict__ out)
{
    const int lane = threadIdx.x;
    const int path = blockIdx.x * 64 + lane;
    const v2f* __restrict__ ct = (const v2f*)((const char*)ws + CTAB_B) + (size_t)path * CPAD;

    v2f e0 = ct[0], e1 = ct[1], e2 = ct[2], e3 = ct[3];
    v2f e4 = ct[4], e5 = ct[5], e6 = ct[6], e7 = ct[7];
    v2f q0 = ct[8], q1 = ct[9], q2 = ct[10], q3 = ct[11];
    v2f q4 = ct[12], q5 = ct[13], q6 = ct[14], q7 = ct[15];
    asm volatile("" : "+v"(e0), "+v"(e1), "+v"(e2), "+v"(e3),
                      "+v"(e4), "+v"(e5), "+v"(e6), "+v"(e7));
    asm volatile("" : "+v"(q0), "+v"(q1), "+v"(q2), "+v"(q3),
                      "+v"(q4), "+v"(q5), "+v"(q6), "+v"(q7));

    float lv = logf(fminf(fmaxf(init_var[path], 0.005f), 0.2f));
    float x  = fmaf(lv, 1.0f / LR, -LM / LR);      // normalized state in [-1, 1]
    const float K1 = LFX * LR;                     // ev = exp2(K1*x + K0)
    const float K0 = LFX * LM;
    const float* __restrict__ dwrow = dW + (size_t)path * NT;
    float* __restrict__ outp = out + path;

    auto STEP = [&](float dw, int tt) {
        float y = fmaf(x + x, x, -1.0f);
        v2f yv = vsplat(y);
        v2f bE = vfma(yv, e7, e6);
        v2f bO = vfma(yv, q7, q6);
        bE = vfma(yv, bE, e5);  bO = vfma(yv, bO, q5);
        bE = vfma(yv, bE, e4);  bO = vfma(yv, bO, q4);
        bE = vfma(yv, bE, e3);  bO = vfma(yv, bO, q3);
        bE = vfma(yv, bE, e2);  bO = vfma(yv, bO, q2);
        bE = vfma(yv, bE, e1);  bO = vfma(yv, bO, q1);
        bE = vfma(yv, bE, e0);  bO = vfma(yv, bO, q0);
        v2f val = vfma(vsplat(x), bO, bE);         // {F, G} in x-space
        x = fmaf(val.y, dw, x + val.x);
        x = __builtin_amdgcn_fmed3f(x, -1.0f, 1.0f);
        float ev = __builtin_amdgcn_exp2f(fmaf(x, K1, K0));   // off-chain
        __builtin_nontemporal_store(ev, outp + (size_t)tt * NPATH);
    };

    // 16-step-deep dW register pipeline (plain cached loads; lines reused 4x)
    v4f buf0 = *(const v4f*)(dwrow + 0);
    v4f buf1 = *(const v4f*)(dwrow + 4);
    v4f buf2 = *(const v4f*)(dwrow + 8);
    v4f buf3 = *(const v4f*)(dwrow + 12);
    for (int t = 0; t < NT; t += 4) {
        v4f cur = buf0;
        buf0 = buf1; buf1 = buf2; buf2 = buf3;
        if (t + 16 < NT) buf3 = *(const v4f*)(dwrow + t + 16);
        STEP(cur.x, t);
        STEP(cur.y, t + 1);
        STEP(cur.z, t + 2);
        STEP(cur.w, t + 3);
    }
}

extern "C" void kernel_launch(void* const* d_in, const int* in_sizes, int n_in,
                              void* d_out, int out_size, void* d_ws, size_t ws_size,
                              hipStream_t stream) {
    const float* init_var = (const float*)d_in[0];
    const float* sig      = (const float*)d_in[1];
    const float* dW       = (const float*)d_in[2];
    const float* dtp      = (const float*)d_in[3];
    const float* drw1     = (const float*)d_in[4];
    const float* drb1     = (const float*)d_in[5];
    const float* drw2     = (const float*)d_in[6];
    const float* drb2     = (const float*)d_in[7];
    const float* drw3     = (const float*)d_in[8];
    const float* drb3     = (const float*)d_in[9];
    const float* dfw1     = (const float*)d_in[10];
    const float* dfb1     = (const float*)d_in[11];
    const float* dfw2     = (const float*)d_in[12];
    const float* dfb2     = (const float*)d_in[13];
    const float* dfw3     = (const float*)d_in[14];
    const float* dfb3     = (const float*)d_in[15];
    float* out = (float*)d_out;
    float* ws  = (float*)d_ws;

    hipLaunchKernelGGL(prep_kernel, dim3(1), dim3(256), 0, stream,
                       drw1, drw2, drb2, drw3, drb3,
                       dfw1, dfw2, dfb2, dfw3, dfb3, dtp, ws);
    hipLaunchKernelGGL(build_kernel, dim3(NPATH), dim3(64), 0, stream,
                       sig, drw1, drb1, dfw1, dfb1,
                       ws, (v2f*)((char*)ws + CTAB_B));
    hipLaunchKernelGGL(scan_kernel, dim3(NPATH / 64), dim3(64), 0, stream,
                       init_var, dW, ws, out);
}

// Round 16
// 215.309 us; speedup vs baseline: 1.6425x; 1.0477x over previous
//
#include <hip/hip_runtime.h>
#include <math.h>

#define NPATH 8192
#define NT    2048
#define NCF   6                 // even/odd coeffs each (deg 5 in y; full deg 11)
#define CPAD  16                // padded v2f stride per path
#define LM    (-3.75f)          // lv-range center  (lv in [-7, -0.5])
#define LR    (3.25f)           // lv-range half-width
#define SFX   2.8853900817779268f   // 2*log2(e)
#define LFX   1.4426950408889634f   // log2(e)

typedef float v2f __attribute__((ext_vector_type(2)));
typedef float v4f __attribute__((ext_vector_type(4)));

// ws float layout
#define W2P_F   0        // v2f w2pairs[k*32+j] = {W2dr[j][k], W2df[j][k]}  (2048 floats)
#define W1VP_F  2048     // v2f w1v pairs [32]
#define W3P_F   2112     // v2f w3 pairs  [32]
#define B2P_F   2176     // v2f b2 pairs  [32]
#define CST_F   2240     // b3dr, b3df, dt
#define CTAB_B  16384    // byte offset: v2f ctab[path][CPAD] = {mE0..mE5, mO0..mO5}

// TM[i][k] = coefficient of y^k in T_i(y), i,k in [0,5] (row-major, 6x6)
__device__ const float TMAT[36] = {
  1,0,0,0,0,0,
  0,1,0,0,0,0,
  -1,0,2,0,0,0,
  0,-3,0,4,0,0,
  1,0,-8,0,8,0,
  0,5,0,-20,0,16
};

__device__ __forceinline__ v2f vsplat(float x) { return (v2f){x, x}; }
__device__ __forceinline__ v2f vfma(v2f a, v2f b, v2f c) { return __builtin_elementwise_fma(a, b, c); }

__device__ __forceinline__ float tanh1(float z) {   // tanh(z) via exp2
    float e = __builtin_amdgcn_exp2f(SFX * z);
    return fmaf(__builtin_amdgcn_rcpf(1.0f + e), -2.0f, 1.0f);
}
__device__ __forceinline__ float sig1(float z) {    // sigmoid(z)
    float e = __builtin_amdgcn_exp2f(-LFX * z);
    return __builtin_amdgcn_rcpf(1.0f + e);
}
__device__ __forceinline__ v2f tanh2(v2f z) {
    v2f r; r.x = tanh1(z.x); r.y = tanh1(z.y); return r;
}

__global__ void prep_kernel(const float* __restrict__ drw1,
                            const float* __restrict__ drw2, const float* __restrict__ drb2,
                            const float* __restrict__ drw3, const float* __restrict__ drb3,
                            const float* __restrict__ dfw1,
                            const float* __restrict__ dfw2, const float* __restrict__ dfb2,
                            const float* __restrict__ dfw3, const float* __restrict__ dfb3,
                            const float* __restrict__ dtp, float* __restrict__ ws)
{
    int tid = threadIdx.x;
    for (int idx = tid; idx < 1024; idx += 256) {
        int k = idx >> 5, j = idx & 31;
        ws[W2P_F + 2 * idx]     = drw2[j * 32 + k];   // W2[j][k] pairs, k-major
        ws[W2P_F + 2 * idx + 1] = dfw2[j * 32 + k];
    }
    if (tid < 32) {
        ws[W1VP_F + 2 * tid]     = drw1[tid * 16 + 15];
        ws[W1VP_F + 2 * tid + 1] = dfw1[tid * 16 + 15];
        ws[W3P_F + 2 * tid]      = drw3[tid];
        ws[W3P_F + 2 * tid + 1]  = dfw3[tid];
        ws[B2P_F + 2 * tid]      = drb2[tid];
        ws[B2P_F + 2 * tid + 1]  = dfb2[tid];
    }
    if (tid == 0) {
        ws[CST_F]     = drb3[0];
        ws[CST_F + 1] = dfb3[0];
        ws[CST_F + 2] = dtp[0];
    }
}

// One 64-lane wave per path. Lane j evaluates both nets at Cheb node
// x_j = cos((j+.5)pi/64); even/odd split via shfl_xor(63); 32-lane DCT
// butterflies give Cheb coeffs of E(y),O(y) (deg 5 each); per-lane
// Cheb->monomial conversion. Coeffs prescaled by 1/LR (x-space state).
// O_F gets +1 on its constant term so the scan update is a single fma:
// x' = (E_F + x*(O_F+1)) + dw*(E_G + x*O_G).
__global__ __launch_bounds__(64) void build_kernel(
    const float* __restrict__ sig,
    const float* __restrict__ drw1, const float* __restrict__ drb1,
    const float* __restrict__ dfw1, const float* __restrict__ dfb1,
    const float* __restrict__ wconst, v2f* __restrict__ ctab)
{
    const int p = blockIdx.x;
    const int j = threadIdx.x;
    __shared__ v2f spv[32];            // pre pairs {dr, df} per hidden unit
    {
        int u = j & 31, net = j >> 5;
        const float* w1 = net ? dfw1 : drw1;
        const float* b1 = net ? dfb1 : drb1;
        float acc = b1[u];
#pragma unroll
        for (int m = 0; m < 15; ++m) acc = fmaf(sig[p * 15 + m], w1[u * 16 + m], acc);
        ((float*)spv)[2 * u + net] = acc;
    }
    __syncthreads();

    const float th = ((float)j + 0.5f) * (float)(M_PI / 64.0);
    const float xj = __cosf(th);
    const float v  = (LM + LR * xj) + 4.0f;        // v = lv + 4 at this node

    const v2f* __restrict__ w2p  = (const v2f*)(wconst + W2P_F);
    const v2f* __restrict__ w1vp = (const v2f*)(wconst + W1VP_F);
    const v2f* __restrict__ w3p  = (const v2f*)(wconst + W3P_F);
    const v2f* __restrict__ b2p  = (const v2f*)(wconst + B2P_F);

    v2f z3 = (v2f){wconst[CST_F], wconst[CST_F + 1]};

#pragma unroll
    for (int c = 0; c < 2; ++c) {          // two chunks of 16 output units
        v2f acc[16];
#pragma unroll
        for (int q = 0; q < 16; ++q) acc[q] = b2p[c * 16 + q];

#pragma unroll 8
        for (int k = 0; k < 32; ++k) {     // h recomputed per chunk
            v2f pre = spv[k];
            v2f z   = vfma(vsplat(v), w1vp[k], pre);
            v2f h   = tanh2(z);
            const v2f* col = w2p + k * 32 + c * 16;   // uniform -> s_load
#pragma unroll
            for (int q = 0; q < 16; ++q) acc[q] = vfma(col[q], h, acc[q]);
        }
#pragma unroll
        for (int q = 0; q < 16; ++q) {
            v2f a2 = tanh2(acc[q]);
            z3 = vfma(w3p[c * 16 + q], a2, z3);
        }
    }

    float dt = wconst[CST_F + 2];
    v2f Fj;
    Fj.x = 3.0f * tanh1(z3.x) * dt * (1.0f / LR);  // F = drift*dt/LR  (x-space)
    Fj.y = (sig1(z3.y) + 0.1f) * (1.0f / LR);      // G = diffusion/LR (x-space)

    // even/odd split: E = (F(x)+F(-x))/2, O = (F(x)-F(-x))/(2x); partner
    // lane is j^63 (x -> -x).
    v2f Fp;
    Fp.x = __shfl_xor(Fj.x, 63);
    Fp.y = __shfl_xor(Fj.y, 63);
    v2f E = (Fj + Fp) * 0.5f;
    float rx = 0.5f * __builtin_amdgcn_rcpf(xj);
    v2f O = (Fj - Fp) * vsplat(rx);

    // y-nodes: jj = j (half0) / 63-j (half1); theta2 = (jj+.5)pi/32.
    int jj = (j < 32) ? j : 63 - j;
    float th2 = ((float)jj + 0.5f) * (float)(M_PI / 32.0);

    v2f de[NCF], dq[NCF];
#pragma unroll
    for (int k = 0; k < NCF; ++k) {
        float ck = __cosf((float)k * th2);
        v2f tE = E * vsplat(ck);
        v2f tO = O * vsplat(ck);
#pragma unroll
        for (int m = 1; m < 32; m <<= 1) {         // 32-lane butterflies (halves independent)
            tE.x += __shfl_xor(tE.x, m); tE.y += __shfl_xor(tE.y, m);
            tO.x += __shfl_xor(tO.x, m); tO.y += __shfl_xor(tO.y, m);
        }
        float s = (k == 0) ? (1.0f / 32.0f) : (2.0f / 32.0f);
        de[k] = tE * vsplat(s);
        dq[k] = tO * vsplat(s);
    }

    // Cheb -> monomial: lane kk computes m_kk = sum_i d_i * TM[i][kk].
    // Lanes 0..5 -> E coeffs, lanes 16..21 -> O coeffs.
    int kk = j & 15; if (kk > 5) kk = 5;
    v2f m = vsplat(0.0f);
#pragma unroll
    for (int i = 0; i < NCF; ++i) {
        float a = TMAT[i * 6 + kk];
        m = vfma((j < 16) ? de[i] : dq[i], vsplat(a), m);
    }
    if (j == 16) m.x += 1.0f;                      // fold "+x" into O_F constant term
    if (j < 6)                  ctab[(size_t)p * CPAD + j]            = m;
    else if (j >= 16 && j < 22) ctab[(size_t)p * CPAD + 6 + (j - 16)] = m;
}

// One lane per path, no LDS, no memory on the chain. 12 NAMED v2f coeffs,
// asm-pinned. Per step (~19 instr, ~9-dep chain): y = 2x^2-1, y2, y4;
// Estrin pairs for E and O (deg-5 each, {F,G} packed); val = fma(x,O,E);
// x = fma(val.y, dw, val.x); med3 clamp; exp2+store off-chain.
__global__ __launch_bounds__(64) __attribute__((amdgpu_waves_per_eu(1, 2)))
void scan_kernel(
    const float* __restrict__ init_var,
    const float* __restrict__ dW,
    const float* __restrict__ ws,
    float* __restrict__ out)
{
    const int lane = threadIdx.x;
    const int path = blockIdx.x * 64 + lane;
    const v2f* __restrict__ ct = (const v2f*)((const char*)ws + CTAB_B) + (size_t)path * CPAD;

    v2f e0 = ct[0], e1 = ct[1], e2 = ct[2], e3 = ct[3], e4 = ct[4], e5 = ct[5];
    v2f q0 = ct[6], q1 = ct[7], q2 = ct[8], q3 = ct[9], q4 = ct[10], q5 = ct[11];
    asm volatile("" : "+v"(e0), "+v"(e1), "+v"(e2), "+v"(e3), "+v"(e4), "+v"(e5));
    asm volatile("" : "+v"(q0), "+v"(q1), "+v"(q2), "+v"(q3), "+v"(q4), "+v"(q5));

    float lv = logf(fminf(fmaxf(init_var[path], 0.005f), 0.2f));
    float x  = fmaf(lv, 1.0f / LR, -LM / LR);      // normalized state in [-1, 1]
    const float K1 = LFX * LR;                     // ev = exp2(K1*x + K0)
    const float K0 = LFX * LM;
    const float* __restrict__ dwrow = dW + (size_t)path * NT;
    float* __restrict__ outp = out + path;

    auto STEP = [&](float dw, int tt) {
        float y  = fmaf(x + x, x, -1.0f);
        float y2 = y * y;
        v2f yv = vsplat(y), y2v = vsplat(y2);
        v2f eA = vfma(yv, e1, e0);
        v2f eB = vfma(yv, e3, e2);
        v2f eC = vfma(yv, e5, e4);
        v2f qA = vfma(yv, q1, q0);
        v2f qB = vfma(yv, q3, q2);
        v2f qC = vfma(yv, q5, q4);
        float y4 = y2 * y2;
        v2f y4v = vsplat(y4);
        v2f bE = vfma(y2v, eB, eA);  bE = vfma(y4v, eC, bE);
        v2f bO = vfma(y2v, qB, qA);  bO = vfma(y4v, qC, bO);
        v2f val = vfma(vsplat(x), bO, bE);         // {x'+F (pre-dw), G}
        x = fmaf(val.y, dw, val.x);
        x = __builtin_amdgcn_fmed3f(x, -1.0f, 1.0f);
        float ev = __builtin_amdgcn_exp2f(fmaf(x, K1, K0));   // off-chain
        __builtin_nontemporal_store(ev, outp + (size_t)tt * NPATH);
    };

    // 16-step-deep dW register pipeline (plain cached loads; lines reused 4x)
    v4f buf0 = *(const v4f*)(dwrow + 0);
    v4f buf1 = *(const v4f*)(dwrow + 4);
    v4f buf2 = *(const v4f*)(dwrow + 8);
    v4f buf3 = *(const v4f*)(dwrow + 12);
    for (int t = 0; t < NT; t += 4) {
        v4f cur = buf0;
        buf0 = buf1; buf1 = buf2; buf2 = buf3;
        if (t + 16 < NT) buf3 = *(const v4f*)(dwrow + t + 16);
        STEP(cur.x, t);
        STEP(cur.y, t + 1);
        STEP(cur.z, t + 2);
        STEP(cur.w, t + 3);
    }
}

extern "C" void kernel_launch(void* const* d_in, const int* in_sizes, int n_in,
                              void* d_out, int out_size, void* d_ws, size_t ws_size,
                              hipStream_t stream) {
    const float* init_var = (const float*)d_in[0];
    const float* sig      = (const float*)d_in[1];
    const float* dW       = (const float*)d_in[2];
    const float* dtp      = (const float*)d_in[3];
    const float* drw1     = (const float*)d_in[4];
    const float* drb1     = (const float*)d_in[5];
    const float* drw2     = (const float*)d_in[6];
    const float* drb2     = (const float*)d_in[7];
    const float* drw3     = (const float*)d_in[8];
    const float* drb3     = (const float*)d_in[9];
    const float* dfw1     = (const float*)d_in[10];
    const float* dfb1     = (const float*)d_in[11];
    const float* dfw2     = (const float*)d_in[12];
    const float* dfb2     = (const float*)d_in[13];
    const float* dfw3     = (const float*)d_in[14];
    const float* dfb3     = (const float*)d_in[15];
    float* out = (float*)d_out;
    float* ws  = (float*)d_ws;

    hipLaunchKernelGGL(prep_kernel, dim3(1), dim3(256), 0, stream,
                       drw1, drw2, drb2, drw3, drb3,
                       dfw1, dfw2, dfb2, dfw3, dfb3, dtp, ws);
    hipLaunchKernelGGL(build_kernel, dim3(NPATH), dim3(64), 0, stream,
                       sig, drw1, drb1, dfw1, dfb1,
                       ws, (v2f*)((char*)ws + CTAB_B));
    hipLaunchKernelGGL(scan_kernel, dim3(NPATH / 64), dim3(64), 0, stream,
                       init_var, dW, ws, out);
}